// Round 15
// baseline (437.491 us; speedup 1.0000x reference)
//
#include <hip/hip_runtime.h>
#include <hip/hip_bf16.h>
#include <math.h>

#define T_TOK 8192
#define D_DIM 2048
#define O_DIM 2048
#define E_NUM 8

typedef __bf16 bf16_t;
typedef __bf16 bf16x8 __attribute__((ext_vector_type(8)));
typedef float fx4 __attribute__((ext_vector_type(4)));
typedef unsigned short us4 __attribute__((ext_vector_type(4)));

__device__ __forceinline__ unsigned short f2bf(float f) {
    unsigned int u = __builtin_bit_cast(unsigned int, f);
    u += 0x7FFFu + ((u >> 16) & 1u);           // round-to-nearest-even
    return (unsigned short)(u >> 16);
}

__device__ __forceinline__ void gll16(const void* g, void* l) {
    __builtin_amdgcn_global_load_lds(
        (const __attribute__((address_space(1))) void*)g,
        (__attribute__((address_space(3))) void*)l, 16, 0, 0);
}

// ---------------------------------------------------------------- convert W
// Also zeroes cnt (block 0); convert_w completes before gate (stream order).
__global__ __launch_bounds__(256) void convert_w_kernel(
    const float* __restrict__ w, bf16_t* __restrict__ wb, int* __restrict__ cnt) {
    if (blockIdx.x == 0 && threadIdx.x < 128) cnt[threadIdx.x] = 0;
    long base = (long)blockIdx.x * 2048 + threadIdx.x;
    const float4* w4 = (const float4*)w;
    us4* o4 = (us4*)wb;
    float4 v[8];
#pragma unroll
    for (int k = 0; k < 8; ++k) v[k] = w4[base + k * 256];
#pragma unroll
    for (int k = 0; k < 8; ++k) {
        us4 o = { f2bf(v[k].x), f2bf(v[k].y), f2bf(v[k].z), f2bf(v[k].w) };
        o4[base + k * 256] = o;
    }
}

// ---------------------------------------------------------------- gating
__global__ __launch_bounds__(256) void gate_kernel(
    const float* __restrict__ x, const float* __restrict__ gw,
    bf16_t* __restrict__ xb, int* __restrict__ cnt,
    int* __restrict__ tok_list, float* __restrict__ wgt_list) {
    int wid = threadIdx.x >> 6, lane = threadIdx.x & 63;
    int t = blockIdx.x * 4 + wid;

    const float4* xrow = (const float4*)(x + (size_t)t * D_DIM);
    float4 xv[8];
#pragma unroll
    for (int i = 0; i < 8; ++i) xv[i] = xrow[i * 64 + lane];

    float acc[E_NUM];
#pragma unroll
    for (int e = 0; e < E_NUM; ++e) {
        const float4* gr = (const float4*)(gw + (size_t)e * D_DIM);
        float s = 0.f;
#pragma unroll
        for (int i = 0; i < 8; ++i) {
            float4 g = gr[i * 64 + lane];
            s += xv[i].x * g.x + xv[i].y * g.y + xv[i].z * g.z + xv[i].w * g.w;
        }
        acc[e] = s;
    }
#pragma unroll
    for (int m = 1; m < 64; m <<= 1) {
#pragma unroll
        for (int e = 0; e < E_NUM; ++e) acc[e] += __shfl_xor(acc[e], m, 64);
    }

    us4* xbr = (us4*)(xb + (size_t)t * D_DIM);
#pragma unroll
    for (int i = 0; i < 8; ++i) {
        us4 o = { f2bf(xv[i].x), f2bf(xv[i].y), f2bf(xv[i].z), f2bf(xv[i].w) };
        xbr[i * 64 + lane] = o;
    }

    if (lane == 0) {
        int e0 = 0; float v0 = acc[0];
#pragma unroll
        for (int e = 1; e < E_NUM; ++e)
            if (acc[e] > v0) { v0 = acc[e]; e0 = e; }
        int e1 = -1; float v1 = -INFINITY;
#pragma unroll
        for (int e = 0; e < E_NUM; ++e)
            if (e != e0 && acc[e] > v1) { v1 = acc[e]; e1 = e; }
        float p1 = expf(v1 - v0);
        float denom = 1.f + p1;
        float w0 = 1.f / denom, w1 = p1 / denom;
        int s0 = atomicAdd(&cnt[e0 * 16], 1);
        tok_list[e0 * T_TOK + s0] = (t << 1);      // slot 0 -> out
        wgt_list[e0 * T_TOK + s0] = w0;
        int s1 = atomicAdd(&cnt[e1 * 16], 1);
        tok_list[e1 * T_TOK + s1] = (t << 1) | 1;  // slot 1 -> part
        wgt_list[e1 * T_TOK + s1] = w1;
    }
}

// ---------------------------------------------------------------- expert GEMM
// WAVE-AUTONOMOUS: zero inner-loop barriers. Block tile 128x256, 8 waves in
// a 2x4 grid; each wave owns a PRIVATE 64x64 output tile and a PRIVATE 16KB
// LDS double-buffer (A 4KB + B 4KB per buf). BK=32, NT=64 K-tiles.
//   Rationale: r6-r13 isolated schedule(x3), bank conflicts(->0), XCD
//   locality, occupancy, A-contiguity — all null; every variant convoys all
//   8 waves on a per-phase barrier+waitcnt, paying the SLOWEST wave's
//   staging tail (gathered A rows + 8MB W_e > 4MB L2 -> stragglers to HBM).
//   Per-wave pipeline decouples: vmcnt(8) waits only on OWN loads issued 2
//   tiles ago (~700cyc slack); lgkmcnt(0) after MFMA retires own ds_reads
//   before own overwrite. No cross-wave hazards by construction.
// Verified pieces reused: (r>>1)&3 XOR swizzle (64B rows, same derivation),
// C/D layout epilogue, e=bid&7 XCD mapping, slot0/slot1 plain stores.
__global__ __launch_bounds__(512, 1) void expert_gemm(
    const bf16_t* __restrict__ xb, const bf16_t* __restrict__ wb,
    const float* __restrict__ eb, const int* __restrict__ cnt,
    const int* __restrict__ tok_list, const float* __restrict__ wgt_list,
    float* __restrict__ out, float* __restrict__ part) {
    int bid = blockIdx.x;
    int e = bid & 7;                          // XCD-resident expert
    int slot = bid >> 3;                      // 0..511 within expert
    int count = cnt[e * 16];
    int mt = (count + 127) >> 7;              // active 128-row m-tiles
    if (slot >= mt * 8) return;
    int m0 = (slot >> 3) * 128;
    int n0 = (slot & 7) * 256;

    __shared__ alignas(16) unsigned char LDSB[131072];  // 8 waves x 16KB
    __shared__ int tok_s[128];
    __shared__ float wgt_s[128];

    int tid = threadIdx.x, wid = tid >> 6, L = tid & 63;
    int wr = wid >> 2, wc = wid & 3;          // 2 x 4 wave grid, 64x64/wave

    if (tid < 128) {
        int idx = m0 + tid;
        if (idx >= count) idx = count - 1;    // clamp; masked in epilogue
        tok_s[tid] = tok_list[e * T_TOK + idx];
        wgt_s[tid] = wgt_list[e * T_TOK + idx];
    }
    __syncthreads();                          // the ONLY barrier

    // staging: call c (0..3) covers 16 rows; lane L: row z=L>>2 in group,
    // dest slot s=L&3, pre-swizzled k-chunk kc = s ^ ((z>>1)&3).
    int z = L >> 2;
    int kc = (L & 3) ^ ((L >> 3) & 3);
    const bf16_t* wbase = wb + (size_t)e * O_DIM * D_DIM;
    const bf16_t* gAr[4];
    const bf16_t* gBr[4];
#pragma unroll
    for (int c = 0; c < 4; ++c) {
        int ra = wr * 64 + c * 16 + z;        // block row (A, gathered)
        gAr[c] = xb + (size_t)(tok_s[ra] >> 1) * D_DIM + kc * 8;
        int rb = n0 + wc * 64 + c * 16 + z;   // W row (B)
        gBr[c] = wbase + (size_t)rb * D_DIM + kc * 8;
    }
    unsigned wbase_lds = (unsigned)wid * 16384u;   // buf d at +d*8192; B at +4096

#define STAGE(d, koff) do {                                                 \
        unsigned bb = wbase_lds + (unsigned)(d) * 8192u;                    \
        _Pragma("unroll") for (int c = 0; c < 4; ++c) {                     \
            gll16(gAr[c] + (koff), LDSB + bb + c * 1024u);                  \
            gll16(gBr[c] + (koff), LDSB + bb + 4096u + c * 1024u);          \
        } } while (0)

    // read: frag row r = f*16 + (L&15), chunk q = L>>4 ->
    // slot = q ^ ((r>>1)&3) = (L>>4) ^ ((L>>1)&3)
    unsigned xorp = ((unsigned)((L >> 4) ^ ((L >> 1) & 3))) * 16u;
    unsigned rsel = (unsigned)(L & 15) * 64u;

    fx4 acc[4][4];
#pragma unroll
    for (int m = 0; m < 4; ++m)
#pragma unroll
        for (int n = 0; n < 4; ++n) acc[m][n] = (fx4)0.f;

    const int NT = D_DIM / 32;                // 64
    STAGE(0, 0);                              // 8 outstanding
    STAGE(1, 32);                             // 16 outstanding

    for (int t = 0; t < NT; ++t) {
        const int d = t & 1;
        unsigned ba = wbase_lds + (unsigned)d * 8192u;
        // own tile-t loads (issued 2 iters ago) complete; t+1's stay in flight
        if (t + 2 < NT) asm volatile("s_waitcnt vmcnt(8)" ::: "memory");
        else            asm volatile("s_waitcnt vmcnt(0)" ::: "memory");
        __builtin_amdgcn_sched_barrier(0);

        bf16x8 aq[4], bq[4];
#pragma unroll
        for (int m = 0; m < 4; ++m)
            aq[m] = *(const bf16x8*)(LDSB + ba + (unsigned)m * 1024u + rsel + xorp);
#pragma unroll
        for (int n = 0; n < 4; ++n)
            bq[n] = *(const bf16x8*)(LDSB + ba + 4096u + (unsigned)n * 1024u + rsel + xorp);

        __builtin_amdgcn_s_setprio(1);
#pragma unroll
        for (int m = 0; m < 4; ++m)
#pragma unroll
            for (int n = 0; n < 4; ++n)
                acc[m][n] = __builtin_amdgcn_mfma_f32_16x16x32_bf16(
                    aq[m], bq[n], acc[m][n], 0, 0, 0);
        __builtin_amdgcn_s_setprio(0);

        // own ds_reads retired -> own buf d may be overwritten (per-wave)
        asm volatile("s_waitcnt lgkmcnt(0)" ::: "memory");
        __builtin_amdgcn_sched_barrier(0);
        if (t + 2 < NT) STAGE(d, (t + 2) * 32);
    }
#undef STAGE

    // epilogue: C/D layout col=L&15, row=(L>>4)*4+j. Plain scatter stores.
    const float* ebias = eb + (size_t)e * O_DIM;
    int rr = L & 15, kq = L >> 4;
#pragma unroll
    for (int n = 0; n < 4; ++n) {
        int gcol = n0 + wc * 64 + n * 16 + rr;
        float bias = ebias[gcol];
#pragma unroll
        for (int m = 0; m < 4; ++m) {
            int rbase = wr * 64 + m * 16 + kq * 4;
#pragma unroll
            for (int j = 0; j < 4; ++j) {
                int r = rbase + j;
                if (m0 + r < count) {
                    int entry = tok_s[r];
                    float v = wgt_s[r] * (acc[m][n][j] + bias);
                    float* dst = (entry & 1) ? part : out;
                    dst[(size_t)(entry >> 1) * O_DIM + gcol] = v;
                }
            }
        }
    }
}

// ---------------------------------------------------------------- combine
__global__ __launch_bounds__(256) void combine_kernel(
    float* __restrict__ out, const float* __restrict__ part, long n4) {
    long i = (long)blockIdx.x * blockDim.x + threadIdx.x;
    long stride = (long)gridDim.x * blockDim.x;
    float4* o4 = (float4*)out;
    const float4* p4 = (const float4*)part;
    for (; i < n4; i += stride) {
        float4 a = o4[i], b = p4[i];
        a.x += b.x; a.y += b.y; a.z += b.z; a.w += b.w;
        o4[i] = a;
    }
}

// ---------------------------------------------------------------- launch
extern "C" void kernel_launch(void* const* d_in, const int* in_sizes, int n_in,
                              void* d_out, int out_size, void* d_ws, size_t ws_size,
                              hipStream_t stream) {
    const float* x        = (const float*)d_in[0];
    const float* gate_w   = (const float*)d_in[1];
    const float* expert_w = (const float*)d_in[2];
    const float* expert_b = (const float*)d_in[3];
    float* out = (float*)d_out;

    char* ws = (char*)d_ws;
    size_t off = 0;
    bf16_t* wb = (bf16_t*)(ws + off);      off += (size_t)E_NUM * O_DIM * D_DIM * 2;
    bf16_t* xb = (bf16_t*)(ws + off);      off += (size_t)T_TOK * D_DIM * 2;
    float*  part = (float*)(ws + off);     off += (size_t)T_TOK * O_DIM * 4;
    int*    tok_list = (int*)(ws + off);   off += (size_t)E_NUM * T_TOK * 4;
    float*  wgt_list = (float*)(ws + off); off += (size_t)E_NUM * T_TOK * 4;
    int*    cnt = (int*)(ws + off);        off += 512;   // 8 counters, 64B apart

    convert_w_kernel<<<4096, 256, 0, stream>>>(expert_w, wb, cnt);
    gate_kernel<<<T_TOK / 4, 256, 0, stream>>>(
        x, gate_w, xb, cnt, tok_list, wgt_list);
    expert_gemm<<<4096, 512, 0, stream>>>(      // 8 experts x 512 worst-case slots
        xb, wb, expert_b, cnt, tok_list, wgt_list, out, part);
    combine_kernel<<<2048, 256, 0, stream>>>(
        out, part, (long)T_TOK * O_DIM / 4);
}

// Round 16
// 326.284 us; speedup vs baseline: 1.3408x; 1.3408x over previous
//
#include <hip/hip_runtime.h>
#include <hip/hip_bf16.h>
#include <math.h>

#define T_TOK 8192
#define D_DIM 2048
#define O_DIM 2048
#define E_NUM 8
#define BM 256
#define BN 256
#define BK 64

typedef __bf16 bf16_t;
typedef __bf16 bf16x8 __attribute__((ext_vector_type(8)));
typedef float fx4 __attribute__((ext_vector_type(4)));
typedef unsigned short us4 __attribute__((ext_vector_type(4)));

__device__ __forceinline__ unsigned short f2bf(float f) {
    unsigned int u = __builtin_bit_cast(unsigned int, f);
    u += 0x7FFFu + ((u >> 16) & 1u);           // round-to-nearest-even
    return (unsigned short)(u >> 16);
}

__device__ __forceinline__ void gll16(const void* g, void* l) {
    __builtin_amdgcn_global_load_lds(
        (const __attribute__((address_space(1))) void*)g,
        (__attribute__((address_space(3))) void*)l, 16, 0, 0);
}

// ---------------------------------------------------------------- convert W
// Also zeroes the cnt counters (fold of the former hipMemsetAsync dispatch).
// convert_w completes before gate starts (stream order) -> race-free.
__global__ __launch_bounds__(256) void convert_w_kernel(
    const float* __restrict__ w, bf16_t* __restrict__ wb, int* __restrict__ cnt) {
    if (blockIdx.x == 0 && threadIdx.x < 128) cnt[threadIdx.x] = 0;
    long base = (long)blockIdx.x * 2048 + threadIdx.x;
    const float4* w4 = (const float4*)w;
    us4* o4 = (us4*)wb;
    float4 v[8];
#pragma unroll
    for (int k = 0; k < 8; ++k) v[k] = w4[base + k * 256];
#pragma unroll
    for (int k = 0; k < 8; ++k) {
        us4 o = { f2bf(v[k].x), f2bf(v[k].y), f2bf(v[k].z), f2bf(v[k].w) };
        o4[base + k * 256] = o;
    }
}

// ---------------------------------------------------------------- gating
// one wave per token; padded counters (cnt[e*16], 64B apart).
__global__ __launch_bounds__(256) void gate_kernel(
    const float* __restrict__ x, const float* __restrict__ gw,
    bf16_t* __restrict__ xb, int* __restrict__ cnt,
    int* __restrict__ tok_list, float* __restrict__ wgt_list) {
    int wid = threadIdx.x >> 6, lane = threadIdx.x & 63;
    int t = blockIdx.x * 4 + wid;

    const float4* xrow = (const float4*)(x + (size_t)t * D_DIM);
    float4 xv[8];
#pragma unroll
    for (int i = 0; i < 8; ++i) xv[i] = xrow[i * 64 + lane];

    float acc[E_NUM];
#pragma unroll
    for (int e = 0; e < E_NUM; ++e) {
        const float4* gr = (const float4*)(gw + (size_t)e * D_DIM);
        float s = 0.f;
#pragma unroll
        for (int i = 0; i < 8; ++i) {
            float4 g = gr[i * 64 + lane];
            s += xv[i].x * g.x + xv[i].y * g.y + xv[i].z * g.z + xv[i].w * g.w;
        }
        acc[e] = s;
    }
#pragma unroll
    for (int m = 1; m < 64; m <<= 1) {
#pragma unroll
        for (int e = 0; e < E_NUM; ++e) acc[e] += __shfl_xor(acc[e], m, 64);
    }

    us4* xbr = (us4*)(xb + (size_t)t * D_DIM);
#pragma unroll
    for (int i = 0; i < 8; ++i) {
        us4 o = { f2bf(xv[i].x), f2bf(xv[i].y), f2bf(xv[i].z), f2bf(xv[i].w) };
        xbr[i * 64 + lane] = o;
    }

    if (lane == 0) {
        int e0 = 0; float v0 = acc[0];
#pragma unroll
        for (int e = 1; e < E_NUM; ++e)
            if (acc[e] > v0) { v0 = acc[e]; e0 = e; }
        int e1 = -1; float v1 = -INFINITY;
#pragma unroll
        for (int e = 0; e < E_NUM; ++e)
            if (e != e0 && acc[e] > v1) { v1 = acc[e]; e1 = e; }
        float p1 = expf(v1 - v0);
        float denom = 1.f + p1;
        float w0 = 1.f / denom, w1 = p1 / denom;
        int s0 = atomicAdd(&cnt[e0 * 16], 1);
        tok_list[e0 * T_TOK + s0] = (t << 1);      // slot 0 -> out
        wgt_list[e0 * T_TOK + s0] = w0;
        int s1 = atomicAdd(&cnt[e1 * 16], 1);
        tok_list[e1 * T_TOK + s1] = (t << 1) | 1;  // slot 1 -> part
        wgt_list[e1 * T_TOK + s1] = w1;
    }
}

// ---------------------------------------------------------------- expert GEMM
// FINAL config (= round 12/14, best measured: gemm 229 us, total 325 us).
// 256x256 tile, BK=64, 8 waves (2Mx4N), 4-phase K-half double-buffer,
// counted vmcnt(8), conflict-free (r>>1)&3 XOR swizzle on both staging
// source and ds_read address (SQ_LDS_BANK_CONFLICT == 0), expert-per-XCD
// mapping (e = bid&7), scatter-A gather via tok_s, plain-store epilogue
// (slot0 -> out, slot1 -> part; no atomics).
// Plateau evidence: schedule x5, conflicts->0, XCD locality, occupancy,
// A-contiguity, barrier-free autonomy — all isolated; only atomics-removal
// (-72us) and XCD mapping (-14us) moved time. Residual 2.6x per-phase gap
// vs dense m201 is the gathered-MoE memory path at the rendezvous.
__global__ __launch_bounds__(512, 1) void expert_gemm(
    const bf16_t* __restrict__ xb, const bf16_t* __restrict__ wb,
    const float* __restrict__ eb, const int* __restrict__ cnt,
    const int* __restrict__ tok_list, const float* __restrict__ wgt_list,
    float* __restrict__ out, float* __restrict__ part) {
    int bid = blockIdx.x;
    int e = bid & 7;                          // XCD-resident expert
    int slot = bid >> 3;                      // 0..255 within expert
    int count = cnt[e * 16];
    int mt = (count + BM - 1) / BM;           // active m-tiles this expert
    if (slot >= mt * 8) return;
    int m0 = (slot >> 3) * BM;
    int n0 = (slot & 7) * BN;

    __shared__ alignas(16) unsigned char LDSB[131072];
    __shared__ int tok_s[BM];
    __shared__ float wgt_s[BM];

    int tid = threadIdx.x, wid = tid >> 6, L = tid & 63;
    int wr = wid >> 2, wc = wid & 3;          // 2 x 4 wave grid

    if (tid < BM) {
        int idx = m0 + tid;
        if (idx >= count) idx = count - 1;    // clamp; masked in epilogue
        tok_s[tid] = tok_list[e * T_TOK + idx];
        wgt_s[tid] = wgt_list[e * T_TOK + idx];
    }
    __syncthreads();

    // ---- staging geometry (conflict-free swizzle) ----
    int rA0 = wid * 16 + (L >> 2);            // call-0 row (0..127)
    int rA1 = rA0 + 128;                      // call-1 row
    int kcol = ((L & 3) ^ ((L >> 3) & 3)) * 8;  // pre-swizzled k-chunk (elems)
    const bf16_t* gA0 = xb + (size_t)(tok_s[rA0] >> 1) * D_DIM + kcol;
    const bf16_t* gA1 = xb + (size_t)(tok_s[rA1] >> 1) * D_DIM + kcol;
    const bf16_t* wbase = wb + (size_t)e * O_DIM * D_DIM;
    const bf16_t* gB0 = wbase + (size_t)(n0 + rA0) * D_DIM + kcol;
    const bf16_t* gB1 = wbase + (size_t)(n0 + rA1) * D_DIM + kcol;
    unsigned sW = wid * 1024;                 // wave-uniform LDS offset, call0

#define STAGE_A(db, hh, koff) do {                                          \
        unsigned bb = (db) * 65536u + (hh) * 16384u + sW;                   \
        gll16(gA0 + (koff), LDSB + bb);                                     \
        gll16(gA1 + (koff), LDSB + bb + 8192); } while (0)
#define STAGE_B(db, hh, koff) do {                                          \
        unsigned bb = (db) * 65536u + 32768u + (hh) * 16384u + sW;          \
        gll16(gB0 + (koff), LDSB + bb);                                     \
        gll16(gB1 + (koff), LDSB + bb + 8192); } while (0)

    // ---- read geometry: slot = (L>>4) ^ ((L>>1)&3) ----
    unsigned xorp = ((unsigned)((L >> 4) ^ ((L >> 1) & 3))) * 16u;
    unsigned rowA = (unsigned)(wr * 128 + (L & 15)) * 64u;
    unsigned rowB = (unsigned)(wc * 64 + (L & 15)) * 64u;

#define LDA(base, MB)                                                       \
    _Pragma("unroll") for (int mm = 0; mm < 4; ++mm)                        \
        aq[mm] = *(const bf16x8*)(LDSB + (base) + rowA + (MB + mm) * 1024u + xorp);
#define LDB(base)                                                           \
    _Pragma("unroll") for (int nn = 0; nn < 4; ++nn)                        \
        bq[nn] = *(const bf16x8*)(LDSB + (base) + 32768u + rowB + nn * 1024u + xorp);
#define PH_MFMA(MB)                                                         \
    __builtin_amdgcn_s_setprio(1);                                          \
    _Pragma("unroll") for (int mm = 0; mm < 4; ++mm)                        \
        _Pragma("unroll") for (int nn = 0; nn < 4; ++nn)                    \
            acc[MB + mm][nn] = __builtin_amdgcn_mfma_f32_16x16x32_bf16(     \
                aq[mm], bq[nn], acc[MB + mm][nn], 0, 0, 0);                  \
    __builtin_amdgcn_s_setprio(0);
#define PHEND_LG  { asm volatile("s_waitcnt lgkmcnt(0)" ::: "memory");      \
                    __builtin_amdgcn_s_barrier();                           \
                    asm volatile("" ::: "memory"); }
#define PHEND_V8  { asm volatile("s_waitcnt vmcnt(8) lgkmcnt(0)" ::: "memory"); \
                    __builtin_amdgcn_s_barrier();                           \
                    asm volatile("" ::: "memory"); }
#define PHEND_V0  { asm volatile("s_waitcnt vmcnt(0) lgkmcnt(0)" ::: "memory"); \
                    __builtin_amdgcn_s_barrier();                           \
                    asm volatile("" ::: "memory"); }

    fx4 acc[8][4];
#pragma unroll
    for (int m = 0; m < 8; ++m)
#pragma unroll
        for (int n = 0; n < 4; ++n) acc[m][n] = (fx4)0.f;

    const int NT = D_DIM / BK;                // 32
    // prologue: tile0 all 4 halves -> dbuf0, tile1 kh0 -> dbuf1.
    STAGE_A(0, 0, 0);   STAGE_B(0, 0, 0);
    STAGE_A(0, 1, 32);  STAGE_B(0, 1, 32);
    STAGE_A(1, 0, 64);  STAGE_B(1, 0, 64);
    PHEND_V8;

    for (int t = 0; t < NT; ++t) {
        const int d = t & 1;
        const unsigned CA = (unsigned)d * 65536u;
        bf16x8 aq[4], bq[4];
        // ---- ph1: kh0, m0-3 (+B kh0) ----
        LDA(CA, 0); LDB(CA);
        if (t + 1 < NT) STAGE_A(d ^ 1, 1, (t + 1) * 64 + 32);
        PHEND_LG;
        PH_MFMA(0);
        // ---- ph2: kh0, m4-7 (B reused in regs) ----
        LDA(CA, 4);
        if (t + 1 < NT) { STAGE_B(d ^ 1, 1, (t + 1) * 64 + 32); PHEND_V8; }
        else            { PHEND_V0; }
        PH_MFMA(4);
        // ---- ph3: kh1, m0-3 (+B kh1) ----
        LDA(CA + 16384u, 0); LDB(CA + 16384u);
        if (t + 2 < NT) STAGE_A(d, 0, (t + 2) * 64);
        PHEND_LG;
        PH_MFMA(0);
        // ---- ph4: kh1, m4-7 ----
        LDA(CA + 16384u, 4);
        if (t + 2 < NT) { STAGE_B(d, 0, (t + 2) * 64); PHEND_V8; }
        else            { PHEND_V0; }
        PH_MFMA(4);
    }
#undef STAGE_A
#undef STAGE_B
#undef LDA
#undef LDB
#undef PH_MFMA
#undef PHEND_LG
#undef PHEND_V8
#undef PHEND_V0

    // epilogue: C/D layout col=L&15, row=(L>>4)*4+j. Plain scatter stores.
    const float* ebias = eb + (size_t)e * O_DIM;
    int rr = L & 15, kq = L >> 4;
#pragma unroll
    for (int n = 0; n < 4; ++n) {
        int gcol = n0 + wc * 64 + n * 16 + rr;
        float bias = ebias[gcol];
#pragma unroll
        for (int m = 0; m < 8; ++m) {
            int rbase = wr * 128 + m * 16 + kq * 4;
#pragma unroll
            for (int j = 0; j < 4; ++j) {
                int r = rbase + j;
                if (m0 + r < count) {
                    int entry = tok_s[r];
                    float v = wgt_s[r] * (acc[m][n][j] + bias);
                    float* dst = (entry & 1) ? part : out;
                    dst[(size_t)(entry >> 1) * O_DIM + gcol] = v;
                }
            }
        }
    }
}

// ---------------------------------------------------------------- combine
__global__ __launch_bounds__(256) void combine_kernel(
    float* __restrict__ out, const float* __restrict__ part, long n4) {
    long i = (long)blockIdx.x * blockDim.x + threadIdx.x;
    long stride = (long)gridDim.x * blockDim.x;
    float4* o4 = (float4*)out;
    const float4* p4 = (const float4*)part;
    for (; i < n4; i += stride) {
        float4 a = o4[i], b = p4[i];
        a.x += b.x; a.y += b.y; a.z += b.z; a.w += b.w;
        o4[i] = a;
    }
}

// ---------------------------------------------------------------- launch
extern "C" void kernel_launch(void* const* d_in, const int* in_sizes, int n_in,
                              void* d_out, int out_size, void* d_ws, size_t ws_size,
                              hipStream_t stream) {
    const float* x        = (const float*)d_in[0];
    const float* gate_w   = (const float*)d_in[1];
    const float* expert_w = (const float*)d_in[2];
    const float* expert_b = (const float*)d_in[3];
    float* out = (float*)d_out;

    char* ws = (char*)d_ws;
    size_t off = 0;
    bf16_t* wb = (bf16_t*)(ws + off);      off += (size_t)E_NUM * O_DIM * D_DIM * 2;
    bf16_t* xb = (bf16_t*)(ws + off);      off += (size_t)T_TOK * D_DIM * 2;
    float*  part = (float*)(ws + off);     off += (size_t)T_TOK * O_DIM * 4;
    int*    tok_list = (int*)(ws + off);   off += (size_t)E_NUM * T_TOK * 4;
    float*  wgt_list = (float*)(ws + off); off += (size_t)E_NUM * T_TOK * 4;
    int*    cnt = (int*)(ws + off);        off += 512;   // 8 counters, 64B apart

    convert_w_kernel<<<4096, 256, 0, stream>>>(expert_w, wb, cnt);
    gate_kernel<<<T_TOK / 4, 256, 0, stream>>>(
        x, gate_w, xb, cnt, tok_list, wgt_list);
    expert_gemm<<<2048, 512, 0, stream>>>(
        xb, wb, expert_b, cnt, tok_list, wgt_list, out, part);
    combine_kernel<<<2048, 256, 0, stream>>>(
        out, part, (long)T_TOK * O_DIM / 4);
}